// Round 5
// baseline (497.545 us; speedup 1.0000x reference)
//
#include <hip/hip_runtime.h>
#include <hip/hip_fp16.h>

#define N_NODES 100000
#define N_EDGES 1600000
#define FEAT 32

#define BUCKET_SHIFT 8                       // 256 nodes per bucket
#define NB 391                               // ceil(100000/256)
#define P1_BLOCKS 256
#define EPB (N_EDGES / P1_BLOCKS)            // 6250 edges per pass-1 block
#define SCAN_N (NB * P1_BLOCKS)              // 100096

// packed-fp16 pair add on int-typed storage
__device__ inline int hadd2i(int a, int b) {
    __half2 r = __hadd2(*reinterpret_cast<__half2*>(&a),
                        *reinterpret_cast<__half2*>(&b));
    return *reinterpret_cast<int*>(&r);
}

// ---------------- CSR build: 2-pass LDS-binned counting sort ----------------

__global__ __launch_bounds__(256) void bin_count(const int* __restrict__ col,
                                                 int* __restrict__ hist) {
    __shared__ int h[NB];
    int t = threadIdx.x;
    for (int i = t; i < NB; i += 256) h[i] = 0;
    __syncthreads();
    int base = blockIdx.x * EPB;
    for (int i = t; i < EPB; i += 256)
        atomicAdd(&h[col[base + i] >> BUCKET_SHIFT], 1);
    __syncthreads();
    for (int i = t; i < NB; i += 256)
        hist[i * P1_BLOCKS + blockIdx.x] = h[i];     // bucket-major
}

__global__ __launch_bounds__(1024) void scan_block(const int* __restrict__ cnt,
                                                   int* __restrict__ ex,
                                                   int* __restrict__ bsum, int n) {
    __shared__ int s[1024];
    int t = threadIdx.x;
    int i = blockIdx.x * 1024 + t;
    int v = (i < n) ? cnt[i] : 0;
    s[t] = v;
    __syncthreads();
    #pragma unroll
    for (int off = 1; off < 1024; off <<= 1) {
        int x = (t >= off) ? s[t - off] : 0;
        __syncthreads();
        s[t] += x;
        __syncthreads();
    }
    if (i < n) ex[i + 1] = s[t];
    if (t == 1023) bsum[blockIdx.x] = s[1023];
}

__global__ __launch_bounds__(128) void scan_sums(int* __restrict__ bsum, int nb) {
    __shared__ int s[128];
    int t = threadIdx.x;
    int v = (t < nb) ? bsum[t] : 0;
    s[t] = v;
    __syncthreads();
    #pragma unroll
    for (int off = 1; off < 128; off <<= 1) {
        int x = (t >= off) ? s[t - off] : 0;
        __syncthreads();
        s[t] += x;
        __syncthreads();
    }
    if (t < nb) bsum[t] = s[t] - v;       // exclusive
}

__global__ __launch_bounds__(1024) void scan_add(int* __restrict__ ex,
                                                 const int* __restrict__ bsum, int n) {
    int i = blockIdx.x * 1024 + threadIdx.x;
    if (i < n) ex[i + 1] += bsum[blockIdx.x];
    if (blockIdx.x == 0 && threadIdx.x == 0) ex[0] = 0;
}

// Pass 1c: scatter packed 4B (local_dst<<17 | src) records, bucket-ordered.
__global__ __launch_bounds__(256) void bin_scatter(const int* __restrict__ row,
                                                   const int* __restrict__ col,
                                                   const int* __restrict__ hoff,
                                                   int* __restrict__ binned) {
    __shared__ int cur[NB];
    int t = threadIdx.x;
    for (int i = t; i < NB; i += 256) cur[i] = hoff[i * P1_BLOCKS + blockIdx.x];
    __syncthreads();
    int base = blockIdx.x * EPB;
    for (int i = t; i < EPB; i += 256) {
        int c = col[base + i];
        int r = row[base + i];
        int p = atomicAdd(&cur[c >> BUCKET_SHIFT], 1);
        binned[p] = ((c & 255) << 17) | r;          // r < 2^17
    }
}

// Pass 2: one block per bucket; exclusive csrc window (no cross-XCD bouncing).
__global__ __launch_bounds__(256) void bucket_sort(const int* __restrict__ binned,
                                                   const int* __restrict__ hoff,
                                                   int* __restrict__ rp,
                                                   int* __restrict__ csrc) {
    __shared__ int h[256];
    int b = blockIdx.x, t = threadIdx.x;
    int bstart = hoff[b * P1_BLOCKS];
    int bend   = hoff[(b + 1) * P1_BLOCKS];
    h[t] = 0;
    __syncthreads();
    for (int p = bstart + t; p < bend; p += 256)
        atomicAdd(&h[binned[p] >> 17], 1);
    __syncthreads();
    int deg = h[t];
    #pragma unroll
    for (int off = 1; off < 256; off <<= 1) {       // inclusive scan
        int x = (t >= off) ? h[t - off] : 0;
        __syncthreads();
        h[t] += x;
        __syncthreads();
    }
    int mystart = bstart + h[t] - deg;
    int node = (b << BUCKET_SHIFT) + t;
    if (node < N_NODES) rp[node] = mystart;
    if (b == NB - 1 && t == 0) rp[N_NODES] = N_EDGES;
    __syncthreads();
    h[t] = mystart;                                  // cursor
    __syncthreads();
    for (int p = bstart + t; p < bend; p += 256) {
        int rec = binned[p];
        int pos = atomicAdd(&h[rec >> 17], 1);
        csrc[pos] = rec & 0x1FFFF;
    }
}

// ---------------- per-layer kernels ----------------

// m[n][f] = relu(b[f] + sum_k h[n][k] * W[k][f]), fp16 out. Zero cross-lane ops:
// per-lane float4 broadcast loads of own-node h, W column from padded LDS transpose.
__global__ __launch_bounds__(256) void node_msg_t(const float* __restrict__ h,
                                                  const float* __restrict__ W,
                                                  const float* __restrict__ b,
                                                  __half* __restrict__ m) {
    __shared__ float WsT[32 * 33];                  // stride 33: conflict-free
    __shared__ float bs[32];
    int t = threadIdx.x;
    for (int i = t; i < 1024; i += 256) {
        int k = i >> 5, f = i & 31;
        WsT[f * 33 + k] = W[i];
    }
    if (t < 32) bs[t] = b[t];
    __syncthreads();

    int node = blockIdx.x * 8 + (t >> 5);           // grid exact: no tail
    int f = t & 31;
    const float4* hp = (const float4*)(h + node * 32);
    const float* wr = &WsT[f * 33];
    float acc = bs[f];
    #pragma unroll
    for (int i = 0; i < 8; i++) {
        float4 q = hp[i];
        acc = fmaf(q.x, wr[4 * i + 0], acc);
        acc = fmaf(q.y, wr[4 * i + 1], acc);
        acc = fmaf(q.z, wr[4 * i + 2], acc);
        acc = fmaf(q.w, wr[4 * i + 3], acc);
    }
    m[node * 32 + f] = __float2half(fmaxf(acc, 0.f));
}

// Paired-feature gather: half-wave per node; lane = (g = lane>>4 neighbor parity,
// fp = lane&15 feature pair). Each load is a half2 (4B) -> one instruction covers
// 2 neighbors via 2 lines; 16 loads per 32-neighbor chunk (vs 32), pk_add_f16
// accumulate, one shfl_xor(16) merges parities. Matvec: h-part shuffle-free
// (float4 broadcast + LDS W^T stride 65), agg-part 16 shuffles.
template <int OUT, bool RELU, bool RESID>
__global__ __launch_bounds__(256) void agg_out_p(const float* __restrict__ h,
                                                 const __half* __restrict__ m,
                                                 const int* __restrict__ rp,
                                                 const int* __restrict__ csrc,
                                                 const float* __restrict__ W,
                                                 const float* __restrict__ b,
                                                 float* __restrict__ out) {
    __shared__ float WsT[32 * 65];                  // WsT[f][j], stride 65: conflict-free
    __shared__ float bs[32];
    int t = threadIdx.x;
    for (int i = t; i < 32 * 65; i += 256) WsT[i] = 0.f;
    __syncthreads();
    for (int i = t; i < 64 * OUT; i += 256) {
        int j = i / OUT, f2 = i % OUT;
        WsT[f2 * 65 + j] = W[i];
    }
    if (t < 32) bs[t] = (t < OUT) ? b[t] : 0.f;
    __syncthreads();

    int node = blockIdx.x * 8 + (t >> 5);           // grid exact: no tail
    int lane = t & 31;
    int g  = lane >> 4;                             // neighbor parity group
    int fp = lane & 15;                             // feature-pair index

    int start = rp[node];
    int end   = rp[node + 1];
    int deg   = end - start;

    int va0 = 0, va1 = 0, va2 = 0, va3 = 0;
    const char* mbase = (const char*)m + (fp << 2);
    for (int p0 = start; p0 < end; p0 += 32) {
        int src_f = (p0 + lane < end) ? csrc[p0 + lane] : 0;
        #pragma unroll
        for (int j = 0; j < 16; j++) {
            int src = __shfl(src_f, 2 * j + g, 32);
            if (p0 + 2 * j + g < end) {
                int val = *reinterpret_cast<const int*>(mbase + ((long)src << 6));
                switch (j & 3) {
                    case 0: va0 = hadd2i(va0, val); break;
                    case 1: va1 = hadd2i(va1, val); break;
                    case 2: va2 = hadd2i(va2, val); break;
                    default: va3 = hadd2i(va3, val); break;
                }
            }
        }
    }
    int vs = hadd2i(hadd2i(va0, va1), hadd2i(va2, va3));
    vs = hadd2i(vs, __shfl_xor(vs, 16, 32));        // lanes 0-15 (dup 16-31): pair sums

    // ---- matvec: lane f owns output feature f (column f of W in LDS) ----
    int f = lane;
    const float* wr = &WsT[f * 65];
    const float4* hp = (const float4*)(h + node * 32);
    float accH = 0.f;
    #pragma unroll
    for (int i = 0; i < 8; i++) {
        float4 q = hp[i];
        accH = fmaf(q.x, wr[4 * i + 0], accH);
        accH = fmaf(q.y, wr[4 * i + 1], accH);
        accH = fmaf(q.z, wr[4 * i + 2], accH);
        accH = fmaf(q.w, wr[4 * i + 3], accH);
    }
    float accA = 0.f;
    #pragma unroll
    for (int pp = 0; pp < 16; pp++) {
        int w = __shfl(vs, pp, 32);
        float2 a2 = __half22float2(*reinterpret_cast<__half2*>(&w));
        accA = fmaf(a2.x, wr[32 + 2 * pp], accA);
        accA = fmaf(a2.y, wr[33 + 2 * pp], accA);
    }
    float rdeg = (deg > 0) ? (1.0f / (float)deg) : 0.f;
    float r = accH + accA * rdeg + bs[f];
    if (f < OUT) {
        if (RELU) r = fmaxf(r, 0.f);
        if (RESID) r += h[node * 32 + f];
        out[node * OUT + f] = r;
    }
}

// ---------------- launch ----------------

extern "C" void kernel_launch(void* const* d_in, const int* in_sizes, int n_in,
                              void* d_out, int out_size, void* d_ws, size_t ws_size,
                              hipStream_t stream) {
    const float* x      = (const float*)d_in[0];
    const int*   ei     = (const int*)d_in[1];     // [2, E]: row then col
    const float* msg_w  = (const float*)d_in[3];   // [4,32,32]
    const float* msg_b  = (const float*)d_in[4];   // [4,32]
    const float* out_w  = (const float*)d_in[5];   // [3,64,32]
    const float* out_b  = (const float*)d_in[6];   // [3,32]
    const float* last_w = (const float*)d_in[7];   // [64,2]
    const float* last_b = (const float*)d_in[8];   // [2]
    float* coords = (float*)d_out;

    const int* row = ei;
    const int* col = ei + N_EDGES;

    // workspace carve-up; binned overlaps hA (dead until layer 0)
    float* hA  = (float*)d_ws;                      // 12.8 MB
    float* hB  = hA + N_NODES * FEAT;               // 12.8 MB
    __half* m  = (__half*)(hB + N_NODES * FEAT);    // 6.4 MB (16B aligned)
    int* rp    = (int*)(m + N_NODES * FEAT);        // [N+1]
    int* hoff  = rp + (N_NODES + 1);                // [SCAN_N+1]
    int* bsum  = hoff + (SCAN_N + 1);               // [128]
    int* hist  = bsum + 128;                        // [SCAN_N]
    int* csrc  = hist + SCAN_N;                     // [E] 6.4 MB
    int* binned = (int*)hA;                         // [E] 6.4 MB (overlap)

    const int SCAN_BLOCKS = (SCAN_N + 1023) / 1024;    // 98
    const int NODE_BLOCKS = N_NODES / 8;               // 12500 exact

    // --- build CSR (by destination), no global atomics ---
    bin_count<<<P1_BLOCKS, 256, 0, stream>>>(col, hist);
    scan_block<<<SCAN_BLOCKS, 1024, 0, stream>>>(hist, hoff, bsum, SCAN_N);
    scan_sums<<<1, 128, 0, stream>>>(bsum, SCAN_BLOCKS);
    scan_add<<<SCAN_BLOCKS, 1024, 0, stream>>>(hoff, bsum, SCAN_N);
    bin_scatter<<<P1_BLOCKS, 256, 0, stream>>>(row, col, hoff, binned);
    bucket_sort<<<NB, 256, 0, stream>>>(binned, hoff, rp, csrc);

    // --- layer 0: x -> hA ---
    node_msg_t<<<NODE_BLOCKS, 256, 0, stream>>>(x, msg_w, msg_b, m);
    agg_out_p<32, true, false><<<NODE_BLOCKS, 256, 0, stream>>>(
        x, m, rp, csrc, out_w, out_b, hA);

    // --- layer 1: hA -> hB (residual) ---
    node_msg_t<<<NODE_BLOCKS, 256, 0, stream>>>(hA, msg_w + 1024, msg_b + 32, m);
    agg_out_p<32, true, true><<<NODE_BLOCKS, 256, 0, stream>>>(
        hA, m, rp, csrc, out_w + 2048, out_b + 32, hB);

    // --- layer 2: hB -> hA (residual) ---
    node_msg_t<<<NODE_BLOCKS, 256, 0, stream>>>(hB, msg_w + 2048, msg_b + 64, m);
    agg_out_p<32, true, true><<<NODE_BLOCKS, 256, 0, stream>>>(
        hB, m, rp, csrc, out_w + 4096, out_b + 64, hA);

    // --- layer 3 (final): hA -> coords [N,2] ---
    node_msg_t<<<NODE_BLOCKS, 256, 0, stream>>>(hA, msg_w + 3072, msg_b + 96, m);
    agg_out_p<2, false, false><<<NODE_BLOCKS, 256, 0, stream>>>(
        hA, m, rp, csrc, last_w, last_b, coords);
}